// Round 6
// baseline (225.164 us; speedup 1.0000x reference)
//
#include <hip/hip_runtime.h>
#include <hip/hip_bf16.h>

// B=2, S=2048, D=1024, H=16, DH=64.  out = causal-MHA(q,k,v) @ wo.T
// bf16 MFMA path, f32 accumulation everywhere.
// Softmax in exp2 domain: Q-projection scale = 0.125 * log2(e).

typedef __bf16 bf16x8 __attribute__((ext_vector_type(8)));
typedef float f32x4 __attribute__((ext_vector_type(4)));

#define AS1 __attribute__((address_space(1)))
#define AS3 __attribute__((address_space(3)))

__device__ __forceinline__ void load_lds16(const void* g, void* l) {
    __builtin_amdgcn_global_load_lds((const AS1 void*)g, (AS3 void*)l, 16, 0, 0);
}

// ---------------- f32 -> bf16 cast, all 7 tensors in one launch ----------------
__global__ __launch_bounds__(256) void cast_all(const float* __restrict__ q,
                                                const float* __restrict__ k,
                                                const float* __restrict__ v,
                                                const float* __restrict__ wq,
                                                const float* __restrict__ wk,
                                                const float* __restrict__ wv,
                                                const float* __restrict__ wo,
                                                __hip_bfloat16* __restrict__ inb,
                                                __hip_bfloat16* __restrict__ wb) {
    const size_t MD = (size_t)4096 * 1024, WD = (size_t)1024 * 1024;
    const int y = blockIdx.y;
    const float* s;
    __hip_bfloat16* d;
    int n4;
    if (y < 3) {
        s = (y == 0) ? q : (y == 1) ? k : v;
        d = inb + (size_t)y * MD;
        n4 = (int)(MD / 4);
    } else {
        s = (y == 3) ? wq : (y == 4) ? wk : (y == 5) ? wv : wo;
        d = wb + (size_t)(y - 3) * WD;
        n4 = (int)(WD / 4);
    }
    for (int i = blockIdx.x * 256 + threadIdx.x; i < n4; i += 1024 * 256) {
        float4 v4 = reinterpret_cast<const float4*>(s)[i];
        union { __hip_bfloat16 h[4]; short4 s4; } u;
        u.h[0] = __float2bfloat16(v4.x);
        u.h[1] = __float2bfloat16(v4.y);
        u.h[2] = __float2bfloat16(v4.z);
        u.h[3] = __float2bfloat16(v4.w);
        reinterpret_cast<short4*>(d)[i] = u.s4;
    }
}

// ---------------- GEMM: C[M,N] = A[M,K] @ W[N,K]^T ----------------
// MODE 0: plain f32 output [4096][1024] (out projection), A = Ab.
// MODE 1: fused QKV (N=3072). A selected per n-region (query/key/value inputs).
//   region 0 -> Qb bf16 [4096][1024], scaled by 0.125*log2(e)  (exp2-domain softmax)
//   region 1 -> Kb bf16 [4096][1024]
//   region 2 -> Vtb bf16 [32 bh][64 dh][2048 s]  (transposed in epilogue)
template <int BM, int MODE>
__global__ __launch_bounds__(256) void gemm_bt(const __hip_bfloat16* __restrict__ Ab,
                                               const __hip_bfloat16* __restrict__ Wb,
                                               float* __restrict__ Cf,
                                               __hip_bfloat16* __restrict__ Qb,
                                               __hip_bfloat16* __restrict__ Kb,
                                               __hip_bfloat16* __restrict__ Vtb) {
    constexpr int Kn = 1024, BK = 32, MW = BM / 32;
    constexpr size_t MD = (size_t)4096 * 1024;

    __shared__ __hip_bfloat16 sA[BM * BK];
    __shared__ __hip_bfloat16 sB[128 * BK];

    const int t = threadIdx.x, w = t >> 6, l = t & 63;
    const int lr = l & 15, lk = (l >> 4) * 8;
    const int mbase = blockIdx.y * BM, nbase = blockIdx.x * 128;
    const int wr = (w >> 1) * (BM / 2), wc = (w & 1) * 64;

    const __hip_bfloat16* A = Ab;
    if constexpr (MODE == 1) A = Ab + (size_t)(nbase >> 10) * MD;

    f32x4 acc[MW][4] = {};

    for (int k0 = 0; k0 < Kn; k0 += BK) {
#pragma unroll
        for (int i = 0; i < BM / 64; i++) {
            const int c = i * 256 + t;
            load_lds16(&A[(size_t)(mbase + (c >> 2)) * Kn + k0 + (c & 3) * 8],
                       &sA[(i * 256 + w * 64) * 8]);
        }
#pragma unroll
        for (int i = 0; i < 2; i++) {
            const int c = i * 256 + t;
            load_lds16(&Wb[(size_t)(nbase + (c >> 2)) * Kn + k0 + (c & 3) * 8],
                       &sB[(i * 256 + w * 64) * 8]);
        }
        __syncthreads();
        bf16x8 af[MW], bfr[4];
#pragma unroll
        for (int m = 0; m < MW; m++) af[m] = *(const bf16x8*)&sA[(wr + m * 16 + lr) * BK + lk];
#pragma unroll
        for (int n = 0; n < 4; n++) bfr[n] = *(const bf16x8*)&sB[(wc + n * 16 + lr) * BK + lk];
#pragma unroll
        for (int m = 0; m < MW; m++)
#pragma unroll
            for (int n = 0; n < 4; n++)
                acc[m][n] = __builtin_amdgcn_mfma_f32_16x16x32_bf16(af[m], bfr[n], acc[m][n], 0, 0, 0);
        __syncthreads();
    }

    // C/D layout: col = lane&15, row = (lane>>4)*4 + reg
    const int row0 = mbase + wr + (l >> 4) * 4;
    if constexpr (MODE == 0) {
#pragma unroll
        for (int m = 0; m < MW; m++)
#pragma unroll
            for (int n = 0; n < 4; n++)
#pragma unroll
                for (int r = 0; r < 4; r++)
                    Cf[(size_t)(row0 + m * 16 + r) * 1024 + nbase + wc + n * 16 + lr] = acc[m][n][r];
    } else {
        const int region = nbase >> 10;
        const int colL = (nbase & 1023) + wc + lr;  // + n*16
        if (region < 2) {
            __hip_bfloat16* Ob = (region == 0) ? Qb : Kb;
            // 0.125 * log2(e): score scale + exp->exp2 conversion folded into Q
            const float alpha = (region == 0) ? 0.18033688011112042f : 1.0f;
#pragma unroll
            for (int m = 0; m < MW; m++)
#pragma unroll
                for (int n = 0; n < 4; n++)
#pragma unroll
                    for (int r = 0; r < 4; r++)
                        Ob[(size_t)(row0 + m * 16 + r) * 1024 + colL + n * 16] =
                            __float2bfloat16(acc[m][n][r] * alpha);
        } else {
            // V^T: Vtb[(b*16+h)*64 + dh][s], 4 consecutive tokens pack into 8B
#pragma unroll
            for (int m = 0; m < MW; m++) {
                const int s0 = row0 + m * 16;          // token (mult of 4)
                const int b = s0 >> 11, s = s0 & 2047;
#pragma unroll
                for (int n = 0; n < 4; n++) {
                    const int dhg = colL + n * 16;      // 0..1023
                    const size_t idx = ((size_t)((b * 16 + (dhg >> 6)) * 64 + (dhg & 63))) * 2048 + s;
                    union { __hip_bfloat16 h[4]; short4 s4; } u;
#pragma unroll
                    for (int r = 0; r < 4; r++) u.h[r] = __float2bfloat16(acc[m][n][r]);
                    *(short4*)&Vtb[idx] = u.s4;
                }
            }
        }
    }
}

// ---------------- causal flash attention (swapped QK^T, in-lane softmax) ----------------
// Q,K dense bf16 [4096][1024]; V^T [bh][64 dh][2048 s].
// One 64-row q-tile per block (grid 1024 = 4 blocks/CU), longest-first per XCD.
// Swapped S^T = mfma(K,Q): lane holds 16 kv-entries of ONE q-row -> in-lane softmax.
// exp2-domain softmax (scale folded into Q), defer-max THR=8, setprio on MFMA.
__device__ __forceinline__ bf16x8 rd8(const __hip_bfloat16* tile, int row, int colb) {
    return *(const bf16x8*)((const char*)tile + row * 128 + (colb ^ ((row & 7) << 4)));
}

__device__ __forceinline__ void stage_kv(const char* Kg, const char* Vg, void* ksb, void* vsb, int t) {
#pragma unroll
    for (int i = 0; i < 2; i++) {
        const int c = i * 256 + t, row = c >> 3;
        const int colb = ((c & 7) * 16) ^ ((row & 7) << 4);
        load_lds16(Kg + (size_t)row * 2048 + colb, (char*)ksb + (i * 256 + (t & 192)) * 16);
    }
#pragma unroll
    for (int i = 0; i < 2; i++) {
        const int c = i * 256 + t, row = c >> 3;
        const int colb = ((c & 7) * 16) ^ ((row & 7) << 4);
        load_lds16(Vg + (size_t)row * 4096 + colb, (char*)vsb + (i * 256 + (t & 192)) * 16);
    }
}

__global__ __launch_bounds__(256, 4) void attn_causal(const __hip_bfloat16* __restrict__ Qb,
                                                      const __hip_bfloat16* __restrict__ Kb,
                                                      const __hip_bfloat16* __restrict__ Vtb,
                                                      __hip_bfloat16* __restrict__ X) {
    constexpr int S = 2048;
    // grid 1024: xcd = i&7 (HW round-robin), 4 bh per XCD (L2-resident K/V),
    // qt descending within XCD -> longest blocks dispatch first.
    const int i0 = blockIdx.x;
    const int j = i0 >> 3;
    const int bh = (i0 & 7) * 4 + (j & 3);
    const int qt = 31 - (j >> 2);
    const int b = bh >> 4, h = bh & 15;

    __shared__ __hip_bfloat16 Ks[2][4096];  // [64 kv][64 dh] swizzled
    __shared__ __hip_bfloat16 Vs[2][4096];  // [64 dh][64 kv] swizzled
    __shared__ __hip_bfloat16 Pl[4 * 1024]; // per-wave [16 q][64 kv] swizzled

    const int t = threadIdx.x, w = t >> 6, l = t & 63;
    const int lr = l & 15, lg = l >> 4, lk = lg * 8;

    const __hip_bfloat16* Qbh = Qb + (size_t)b * S * 1024 + h * 64;
    const char* Kbh = (const char*)(Kb + (size_t)b * S * 1024 + h * 64);
    const char* Vbh = (const char*)(Vtb + (size_t)bh * 64 * 2048);
    __hip_bfloat16* Xbh = X + (size_t)b * S * 1024 + h * 64;

    const int qrow = qt * 64 + w * 16;
    bf16x8 qf[2];
#pragma unroll
    for (int kk = 0; kk < 2; kk++)
        qf[kk] = *(const bf16x8*)&Qbh[(size_t)(qrow + lr) * 1024 + kk * 32 + lk];

    f32x4 xacc[4] = {};
    float m = -1e30f, lsum = 0.f;  // softmax state for q = qrow + lr (per lane)

    stage_kv(Kbh, Vbh, &Ks[0][0], &Vs[0][0], t);

    const int total = qt + 1;
    for (int kt = 0; kt < total; ++kt) {
        if (kt + 1 < total) {
            stage_kv(Kbh + (size_t)((kt + 1) * 64) * 2048, Vbh + (size_t)(kt + 1) * 128,
                     &Ks[(kt + 1) & 1][0], &Vs[(kt + 1) & 1][0], t);
            asm volatile("s_waitcnt vmcnt(4)" ::: "memory");
        } else {
            asm volatile("s_waitcnt vmcnt(0)" ::: "memory");
        }
        __builtin_amdgcn_s_barrier();

        const __hip_bfloat16* Kt = &Ks[kt & 1][0];
        const __hip_bfloat16* Vt = &Vs[kt & 1][0];

        // ---- S^T = K @ Q^T : lane holds S[kv = n*16 + lg*4 + r][q = qrow + lr] ----
        f32x4 sacc[4] = {};
        __builtin_amdgcn_s_setprio(1);
#pragma unroll
        for (int kk = 0; kk < 2; kk++)
#pragma unroll
            for (int n = 0; n < 4; n++)
                sacc[n] = __builtin_amdgcn_mfma_f32_16x16x32_bf16(
                    rd8(Kt, n * 16 + lr, kk * 64 + lg * 16), qf[kk], sacc[n], 0, 0, 0);
        __builtin_amdgcn_s_setprio(0);

        // ---- causal mask on diagonal tile ----
        if (kt == qt) {
            const int qg = qrow + lr;
#pragma unroll
            for (int n = 0; n < 4; n++)
#pragma unroll
                for (int r = 0; r < 4; r++)
                    if (kt * 64 + n * 16 + lg * 4 + r > qg) sacc[n][r] = -1e30f;
        }

        // ---- in-lane max over this lane's 16 kv entries + 2-shfl reduce ----
        float tm = fmaxf(fmaxf(sacc[0][0], sacc[0][1]), fmaxf(sacc[0][2], sacc[0][3]));
#pragma unroll
        for (int n = 1; n < 4; n++)
            tm = fmaxf(tm, fmaxf(fmaxf(sacc[n][0], sacc[n][1]), fmaxf(sacc[n][2], sacc[n][3])));
        tm = fmaxf(tm, __shfl_xor(tm, 16, 64));
        tm = fmaxf(tm, __shfl_xor(tm, 32, 64));

        // ---- defer-max: only rescale when max grew by > 8 (P bounded by 2^8) ----
        if (!__all(tm <= m + 8.0f)) {
            const float mn = fmaxf(m, tm);
            const float sc = exp2f(m - mn);
            m = mn;
            lsum *= sc;
#pragma unroll
            for (int r = 0; r < 4; r++) {
                const float bsc = __shfl(sc, (lg << 2) + r, 64);
#pragma unroll
                for (int dd = 0; dd < 4; dd++) xacc[dd][r] *= bsc;
            }
        }

        // ---- P = exp2(S - m), in-lane sum ----
        float pr[4][4], ps = 0.f;
#pragma unroll
        for (int n = 0; n < 4; n++)
#pragma unroll
            for (int r = 0; r < 4; r++) {
                const float pv = exp2f(sacc[n][r] - m);
                pr[n][r] = pv;
                ps += pv;
            }
        ps += __shfl_xor(ps, 16, 64);
        ps += __shfl_xor(ps, 32, 64);
        lsum += ps;

        // ---- P^T -> per-wave LDS (row = q = lr, 4 consecutive kv pack to b64) ----
#pragma unroll
        for (int n = 0; n < 4; n++) {
            union { __hip_bfloat16 hh[4]; short4 s4; } u;
#pragma unroll
            for (int r = 0; r < 4; r++) u.hh[r] = __float2bfloat16(pr[n][r]);
            *(short4*)((char*)Pl + w * 2048 + lr * 128 +
                       ((n * 32 + lg * 8) ^ ((lr & 7) << 4))) = u.s4;
        }

        // ---- PV: X[16 q][64 dh] += P @ V ----
        __builtin_amdgcn_s_setprio(1);
#pragma unroll
        for (int kk = 0; kk < 2; kk++) {
            const bf16x8 pa = *(const bf16x8*)((const char*)Pl + w * 2048 + lr * 128 +
                                               ((kk * 64 + lg * 16) ^ ((lr & 7) << 4)));
#pragma unroll
            for (int dd = 0; dd < 4; dd++)
                xacc[dd] = __builtin_amdgcn_mfma_f32_16x16x32_bf16(
                    pa, rd8(Vt, dd * 16 + lr, kk * 64 + lg * 16), xacc[dd], 0, 0, 0);
        }
        __builtin_amdgcn_s_setprio(0);
        __builtin_amdgcn_s_barrier();
    }

    // ---- epilogue: broadcast 1/lsum to xacc lanes, store ----
    const float inv = 1.0f / lsum;
#pragma unroll
    for (int r = 0; r < 4; r++) {
        const float binv = __shfl(inv, (lg << 2) + r, 64);
#pragma unroll
        for (int dd = 0; dd < 4; dd++)
            Xbh[(size_t)(qrow + lg * 4 + r) * 1024 + dd * 16 + lr] =
                __float2bfloat16(xacc[dd][r] * binv);
    }
}

// ---------------- launch ----------------
extern "C" void kernel_launch(void* const* d_in, const int* in_sizes, int n_in,
                              void* d_out, int out_size, void* d_ws, size_t ws_size,
                              hipStream_t stream) {
    const float* q_in = (const float*)d_in[0];
    const float* k_in = (const float*)d_in[1];
    const float* v_in = (const float*)d_in[2];
    // d_in[3] = causal mask — always tril, exploited structurally
    const float* wq = (const float*)d_in[4];
    const float* wk = (const float*)d_in[5];
    const float* wv = (const float*)d_in[6];
    const float* wo = (const float*)d_in[7];

    const size_t MD = (size_t)4096 * 1024;
    const size_t WD = (size_t)1024 * 1024;

    __hip_bfloat16* ws = (__hip_bfloat16*)d_ws;
    __hip_bfloat16* inb = ws;              // query,key,value bf16 (3*MD)
    __hip_bfloat16* wb = inb + 3 * MD;     // wq,wk,wv,wo bf16 (4*WD, stacked)
    __hip_bfloat16* Qbuf = wb + 4 * WD;    // MD
    __hip_bfloat16* Kbuf = Qbuf + MD;      // MD
    __hip_bfloat16* Vtb = Kbuf + MD;       // MD   [bh][64][2048]
    __hip_bfloat16* xb = Vtb + MD;         // MD   attention output

    cast_all<<<dim3(1024, 7), 256, 0, stream>>>(q_in, k_in, v_in, wq, wk, wv, wo, inb, wb);

    // fused QKV projection, N=3072 (A chosen per region; V written transposed)
    gemm_bt<128, 1><<<dim3(24, 32), 256, 0, stream>>>(inb, wb, nullptr, Qbuf, Kbuf, Vtb);

    // causal attention (per-q-tile blocks, longest-first, XCD-local K/V)
    attn_causal<<<1024, 256, 0, stream>>>(Qbuf, Kbuf, Vtb, xb);

    // output projection -> f32
    gemm_bt<64, 0><<<dim3(8, 64), 256, 0, stream>>>(xb, wb + 3 * WD, (float*)d_out,
                                                    nullptr, nullptr, nullptr);
}

// Round 8
// 215.452 us; speedup vs baseline: 1.0451x; 1.0451x over previous
//
#include <hip/hip_runtime.h>
#include <hip/hip_bf16.h>

// B=2, S=2048, D=1024, H=16, DH=64.  out = causal-MHA(q,k,v) @ wo.T
// bf16 MFMA path, f32 accumulation everywhere.
// Softmax in exp2 domain: Q-projection scale = 0.125 * log2(e).

typedef __bf16 bf16x8 __attribute__((ext_vector_type(8)));
typedef float f32x4 __attribute__((ext_vector_type(4)));

#define AS1 __attribute__((address_space(1)))
#define AS3 __attribute__((address_space(3)))

__device__ __forceinline__ void load_lds16(const void* g, void* l) {
    __builtin_amdgcn_global_load_lds((const AS1 void*)g, (AS3 void*)l, 16, 0, 0);
}

// ---------------- f32 -> bf16 cast, all 7 tensors in one launch ----------------
__global__ __launch_bounds__(256) void cast_all(const float* __restrict__ q,
                                                const float* __restrict__ k,
                                                const float* __restrict__ v,
                                                const float* __restrict__ wq,
                                                const float* __restrict__ wk,
                                                const float* __restrict__ wv,
                                                const float* __restrict__ wo,
                                                __hip_bfloat16* __restrict__ inb,
                                                __hip_bfloat16* __restrict__ wb) {
    const size_t MD = (size_t)4096 * 1024, WD = (size_t)1024 * 1024;
    const int y = blockIdx.y;
    const float* s;
    __hip_bfloat16* d;
    int n4;
    if (y < 3) {
        s = (y == 0) ? q : (y == 1) ? k : v;
        d = inb + (size_t)y * MD;
        n4 = (int)(MD / 4);
    } else {
        s = (y == 3) ? wq : (y == 4) ? wk : (y == 5) ? wv : wo;
        d = wb + (size_t)(y - 3) * WD;
        n4 = (int)(WD / 4);
    }
    for (int i = blockIdx.x * 256 + threadIdx.x; i < n4; i += 1024 * 256) {
        float4 v4 = reinterpret_cast<const float4*>(s)[i];
        union { __hip_bfloat16 h[4]; short4 s4; } u;
        u.h[0] = __float2bfloat16(v4.x);
        u.h[1] = __float2bfloat16(v4.y);
        u.h[2] = __float2bfloat16(v4.z);
        u.h[3] = __float2bfloat16(v4.w);
        reinterpret_cast<short4*>(d)[i] = u.s4;
    }
}

// ---------------- GEMM: C[M,N] = A[M,K] @ W[N,K]^T ----------------
// MODE 0: plain f32 output [4096][1024] (out projection), A = Ab.
// MODE 1: fused QKV (N=3072). A selected per n-region (query/key/value inputs).
//   region 0 -> Qb bf16 [4096][1024], scaled by 0.125*log2(e)  (exp2-domain softmax)
//   region 1 -> Kb bf16 [4096][1024]
//   region 2 -> Vtb bf16 [32 bh][64 dh][2048 s]  (transposed in epilogue)
template <int BM, int MODE>
__global__ __launch_bounds__(256) void gemm_bt(const __hip_bfloat16* __restrict__ Ab,
                                               const __hip_bfloat16* __restrict__ Wb,
                                               float* __restrict__ Cf,
                                               __hip_bfloat16* __restrict__ Qb,
                                               __hip_bfloat16* __restrict__ Kb,
                                               __hip_bfloat16* __restrict__ Vtb) {
    constexpr int Kn = 1024, BK = 32, MW = BM / 32;
    constexpr size_t MD = (size_t)4096 * 1024;

    __shared__ __hip_bfloat16 sA[BM * BK];
    __shared__ __hip_bfloat16 sB[128 * BK];

    const int t = threadIdx.x, w = t >> 6, l = t & 63;
    const int lr = l & 15, lk = (l >> 4) * 8;
    const int mbase = blockIdx.y * BM, nbase = blockIdx.x * 128;
    const int wr = (w >> 1) * (BM / 2), wc = (w & 1) * 64;

    const __hip_bfloat16* A = Ab;
    if constexpr (MODE == 1) A = Ab + (size_t)(nbase >> 10) * MD;

    f32x4 acc[MW][4] = {};

    for (int k0 = 0; k0 < Kn; k0 += BK) {
#pragma unroll
        for (int i = 0; i < BM / 64; i++) {
            const int c = i * 256 + t;
            load_lds16(&A[(size_t)(mbase + (c >> 2)) * Kn + k0 + (c & 3) * 8],
                       &sA[(i * 256 + w * 64) * 8]);
        }
#pragma unroll
        for (int i = 0; i < 2; i++) {
            const int c = i * 256 + t;
            load_lds16(&Wb[(size_t)(nbase + (c >> 2)) * Kn + k0 + (c & 3) * 8],
                       &sB[(i * 256 + w * 64) * 8]);
        }
        __syncthreads();
        bf16x8 af[MW], bfr[4];
#pragma unroll
        for (int m = 0; m < MW; m++) af[m] = *(const bf16x8*)&sA[(wr + m * 16 + lr) * BK + lk];
#pragma unroll
        for (int n = 0; n < 4; n++) bfr[n] = *(const bf16x8*)&sB[(wc + n * 16 + lr) * BK + lk];
#pragma unroll
        for (int m = 0; m < MW; m++)
#pragma unroll
            for (int n = 0; n < 4; n++)
                acc[m][n] = __builtin_amdgcn_mfma_f32_16x16x32_bf16(af[m], bfr[n], acc[m][n], 0, 0, 0);
        __syncthreads();
    }

    // C/D layout: col = lane&15, row = (lane>>4)*4 + reg
    const int row0 = mbase + wr + (l >> 4) * 4;
    if constexpr (MODE == 0) {
#pragma unroll
        for (int m = 0; m < MW; m++)
#pragma unroll
            for (int n = 0; n < 4; n++)
#pragma unroll
                for (int r = 0; r < 4; r++)
                    Cf[(size_t)(row0 + m * 16 + r) * 1024 + nbase + wc + n * 16 + lr] = acc[m][n][r];
    } else {
        const int region = nbase >> 10;
        const int colL = (nbase & 1023) + wc + lr;  // + n*16
        if (region < 2) {
            __hip_bfloat16* Ob = (region == 0) ? Qb : Kb;
            // 0.125 * log2(e): score scale + exp->exp2 conversion folded into Q
            const float alpha = (region == 0) ? 0.18033688011112042f : 1.0f;
#pragma unroll
            for (int m = 0; m < MW; m++)
#pragma unroll
                for (int n = 0; n < 4; n++)
#pragma unroll
                    for (int r = 0; r < 4; r++)
                        Ob[(size_t)(row0 + m * 16 + r) * 1024 + colL + n * 16] =
                            __float2bfloat16(acc[m][n][r] * alpha);
        } else {
            // V^T: Vtb[(b*16+h)*64 + dh][s], 4 consecutive tokens pack into 8B
#pragma unroll
            for (int m = 0; m < MW; m++) {
                const int s0 = row0 + m * 16;          // token (mult of 4)
                const int b = s0 >> 11, s = s0 & 2047;
#pragma unroll
                for (int n = 0; n < 4; n++) {
                    const int dhg = colL + n * 16;      // 0..1023
                    const size_t idx = ((size_t)((b * 16 + (dhg >> 6)) * 64 + (dhg & 63))) * 2048 + s;
                    union { __hip_bfloat16 h[4]; short4 s4; } u;
#pragma unroll
                    for (int r = 0; r < 4; r++) u.h[r] = __float2bfloat16(acc[m][n][r]);
                    *(short4*)&Vtb[idx] = u.s4;
                }
            }
        }
    }
}

// ---------------- causal flash attention (swapped QK^T, in-lane softmax) ----------------
// Q,K dense bf16 [4096][1024]; V^T [bh][64 dh][2048 s].
// One 64-row q-tile per block (grid 1024 = 4 blocks/CU), longest-first per XCD.
// Swapped S^T = mfma(K,Q): lane holds 16 kv-entries of ONE q-row -> in-lane softmax.
// exp2-domain softmax (scale folded into Q), defer-max THR=8.
// NO setprio: 4-wave barrier-synced block is the lockstep regime where it hurts (m190).
__device__ __forceinline__ bf16x8 rd8(const __hip_bfloat16* tile, int row, int colb) {
    return *(const bf16x8*)((const char*)tile + row * 128 + (colb ^ ((row & 7) << 4)));
}

__device__ __forceinline__ void stage_kv(const char* Kg, const char* Vg, void* ksb, void* vsb, int t) {
#pragma unroll
    for (int i = 0; i < 2; i++) {
        const int c = i * 256 + t, row = c >> 3;
        const int colb = ((c & 7) * 16) ^ ((row & 7) << 4);
        load_lds16(Kg + (size_t)row * 2048 + colb, (char*)ksb + (i * 256 + (t & 192)) * 16);
    }
#pragma unroll
    for (int i = 0; i < 2; i++) {
        const int c = i * 256 + t, row = c >> 3;
        const int colb = ((c & 7) * 16) ^ ((row & 7) << 4);
        load_lds16(Vg + (size_t)row * 4096 + colb, (char*)vsb + (i * 256 + (t & 192)) * 16);
    }
}

__global__ __launch_bounds__(256, 4) void attn_causal(const __hip_bfloat16* __restrict__ Qb,
                                                      const __hip_bfloat16* __restrict__ Kb,
                                                      const __hip_bfloat16* __restrict__ Vtb,
                                                      __hip_bfloat16* __restrict__ X) {
    constexpr int S = 2048;
    // grid 1024: xcd = i&7 (HW round-robin), 4 bh per XCD (L2-resident K/V),
    // qt descending within XCD -> longest blocks dispatch first.
    const int i0 = blockIdx.x;
    const int j = i0 >> 3;
    const int bh = (i0 & 7) * 4 + (j & 3);
    const int qt = 31 - (j >> 2);
    const int b = bh >> 4, h = bh & 15;

    __shared__ __hip_bfloat16 Ks[2][4096];  // [64 kv][64 dh] swizzled
    __shared__ __hip_bfloat16 Vs[2][4096];  // [64 dh][64 kv] swizzled
    __shared__ __hip_bfloat16 Pl[4 * 1024]; // per-wave [16 q][64 kv] swizzled

    const int t = threadIdx.x, w = t >> 6, l = t & 63;
    const int lr = l & 15, lg = l >> 4, lk = lg * 8;

    const __hip_bfloat16* Qbh = Qb + (size_t)b * S * 1024 + h * 64;
    const char* Kbh = (const char*)(Kb + (size_t)b * S * 1024 + h * 64);
    const char* Vbh = (const char*)(Vtb + (size_t)bh * 64 * 2048);
    __hip_bfloat16* Xbh = X + (size_t)b * S * 1024 + h * 64;

    const int qrow = qt * 64 + w * 16;
    bf16x8 qf[2];
#pragma unroll
    for (int kk = 0; kk < 2; kk++)
        qf[kk] = *(const bf16x8*)&Qbh[(size_t)(qrow + lr) * 1024 + kk * 32 + lk];

    f32x4 xacc[4] = {};
    float m = -1e30f, lsum = 0.f;  // softmax state for q = qrow + lr (per lane)

    stage_kv(Kbh, Vbh, &Ks[0][0], &Vs[0][0], t);

    const int total = qt + 1;
    for (int kt = 0; kt < total; ++kt) {
        if (kt + 1 < total) {
            stage_kv(Kbh + (size_t)((kt + 1) * 64) * 2048, Vbh + (size_t)(kt + 1) * 128,
                     &Ks[(kt + 1) & 1][0], &Vs[(kt + 1) & 1][0], t);
            asm volatile("s_waitcnt vmcnt(4)" ::: "memory");
        } else {
            asm volatile("s_waitcnt vmcnt(0)" ::: "memory");
        }
        __builtin_amdgcn_s_barrier();

        const __hip_bfloat16* Kt = &Ks[kt & 1][0];
        const __hip_bfloat16* Vt = &Vs[kt & 1][0];

        // ---- S^T = K @ Q^T : lane holds S[kv = n*16 + lg*4 + r][q = qrow + lr] ----
        f32x4 sacc[4] = {};
#pragma unroll
        for (int kk = 0; kk < 2; kk++)
#pragma unroll
            for (int n = 0; n < 4; n++)
                sacc[n] = __builtin_amdgcn_mfma_f32_16x16x32_bf16(
                    rd8(Kt, n * 16 + lr, kk * 64 + lg * 16), qf[kk], sacc[n], 0, 0, 0);

        // ---- causal mask on diagonal tile ----
        if (kt == qt) {
            const int qg = qrow + lr;
#pragma unroll
            for (int n = 0; n < 4; n++)
#pragma unroll
                for (int r = 0; r < 4; r++)
                    if (kt * 64 + n * 16 + lg * 4 + r > qg) sacc[n][r] = -1e30f;
        }

        // ---- in-lane max over this lane's 16 kv entries + 2-shfl reduce ----
        float tm = fmaxf(fmaxf(sacc[0][0], sacc[0][1]), fmaxf(sacc[0][2], sacc[0][3]));
#pragma unroll
        for (int n = 1; n < 4; n++)
            tm = fmaxf(tm, fmaxf(fmaxf(sacc[n][0], sacc[n][1]), fmaxf(sacc[n][2], sacc[n][3])));
        tm = fmaxf(tm, __shfl_xor(tm, 16, 64));
        tm = fmaxf(tm, __shfl_xor(tm, 32, 64));

        // ---- defer-max: only rescale when max grew by > 8 (P bounded by 2^8) ----
        if (!__all(tm <= m + 8.0f)) {
            const float mn = fmaxf(m, tm);
            const float sc = __builtin_amdgcn_exp2f(m - mn);
            m = mn;
            lsum *= sc;
#pragma unroll
            for (int r = 0; r < 4; r++) {
                const float bsc = __shfl(sc, (lg << 2) + r, 64);
#pragma unroll
                for (int dd = 0; dd < 4; dd++) xacc[dd][r] *= bsc;
            }
        }

        // ---- P = exp2(S - m), in-lane sum (native v_exp_f32) ----
        float pr[4][4], ps = 0.f;
#pragma unroll
        for (int n = 0; n < 4; n++)
#pragma unroll
            for (int r = 0; r < 4; r++) {
                const float pv = __builtin_amdgcn_exp2f(sacc[n][r] - m);
                pr[n][r] = pv;
                ps += pv;
            }
        ps += __shfl_xor(ps, 16, 64);
        ps += __shfl_xor(ps, 32, 64);
        lsum += ps;

        // ---- P^T -> per-wave LDS (row = q = lr, 4 consecutive kv pack to b64) ----
#pragma unroll
        for (int n = 0; n < 4; n++) {
            union { __hip_bfloat16 hh[4]; short4 s4; } u;
#pragma unroll
            for (int r = 0; r < 4; r++) u.hh[r] = __float2bfloat16(pr[n][r]);
            *(short4*)((char*)Pl + w * 2048 + lr * 128 +
                       ((n * 32 + lg * 8) ^ ((lr & 7) << 4))) = u.s4;
        }

        // ---- PV: X[16 q][64 dh] += P @ V ----
#pragma unroll
        for (int kk = 0; kk < 2; kk++) {
            const bf16x8 pa = *(const bf16x8*)((const char*)Pl + w * 2048 + lr * 128 +
                                               ((kk * 64 + lg * 16) ^ ((lr & 7) << 4)));
#pragma unroll
            for (int dd = 0; dd < 4; dd++)
                xacc[dd] = __builtin_amdgcn_mfma_f32_16x16x32_bf16(
                    pa, rd8(Vt, dd * 16 + lr, kk * 64 + lg * 16), xacc[dd], 0, 0, 0);
        }
        __builtin_amdgcn_s_barrier();
    }

    // ---- epilogue: broadcast 1/lsum to xacc lanes, store ----
    const float inv = 1.0f / lsum;
#pragma unroll
    for (int r = 0; r < 4; r++) {
        const float binv = __shfl(inv, (lg << 2) + r, 64);
#pragma unroll
        for (int dd = 0; dd < 4; dd++)
            Xbh[(size_t)(qrow + lg * 4 + r) * 1024 + dd * 16 + lr] =
                __float2bfloat16(xacc[dd][r] * binv);
    }
}

// ---------------- launch ----------------
extern "C" void kernel_launch(void* const* d_in, const int* in_sizes, int n_in,
                              void* d_out, int out_size, void* d_ws, size_t ws_size,
                              hipStream_t stream) {
    const float* q_in = (const float*)d_in[0];
    const float* k_in = (const float*)d_in[1];
    const float* v_in = (const float*)d_in[2];
    // d_in[3] = causal mask — always tril, exploited structurally
    const float* wq = (const float*)d_in[4];
    const float* wk = (const float*)d_in[5];
    const float* wv = (const float*)d_in[6];
    const float* wo = (const float*)d_in[7];

    const size_t MD = (size_t)4096 * 1024;
    const size_t WD = (size_t)1024 * 1024;

    __hip_bfloat16* ws = (__hip_bfloat16*)d_ws;
    __hip_bfloat16* inb = ws;              // query,key,value bf16 (3*MD)
    __hip_bfloat16* wb = inb + 3 * MD;     // wq,wk,wv,wo bf16 (4*WD, stacked)
    __hip_bfloat16* Qbuf = wb + 4 * WD;    // MD
    __hip_bfloat16* Kbuf = Qbuf + MD;      // MD
    __hip_bfloat16* Vtb = Kbuf + MD;       // MD   [bh][64][2048]
    __hip_bfloat16* xb = Vtb + MD;         // MD   attention output

    cast_all<<<dim3(1024, 7), 256, 0, stream>>>(q_in, k_in, v_in, wq, wk, wv, wo, inb, wb);

    // fused QKV projection, N=3072 (A chosen per region; V written transposed)
    gemm_bt<128, 1><<<dim3(24, 32), 256, 0, stream>>>(inb, wb, nullptr, Qbuf, Kbuf, Vtb);

    // causal attention (per-q-tile blocks, longest-first, XCD-local K/V)
    attn_causal<<<1024, 256, 0, stream>>>(Qbuf, Kbuf, Vtb, xb);

    // output projection -> f32
    gemm_bt<64, 0><<<dim3(8, 64), 256, 0, stream>>>(xb, wb + 3 * WD, (float*)d_out,
                                                    nullptr, nullptr, nullptr);
}